// Round 10
// baseline (855.706 us; speedup 1.0000x reference)
//
#include <hip/hip_runtime.h>
#include <math.h>
#include <stdint.h>

#define NB 8
#define CIN 512
#define HW 4096
#define ANUM 9
#define NANC 36864
#define PRE 2000
#define POST 300

// d_out float offsets
#define OUT_LOCS   0
#define OUT_SCORES 1179648
#define OUT_ROIS   1769472
#define OUT_RIDX   1779072
#define OUT_ANC    1781472

typedef _Float16 half8 __attribute__((ext_vector_type(8)));
typedef float f32x4 __attribute__((ext_vector_type(4)));

#define WSCALE 256.0f
#define LSCALE 4096.0f
#define INV_WS (1.0f / 256.0f)
#define INV_LS (1.0f / 4096.0f)
#define XS_STRIDE 40  // halfs per halo position (32 data + 8 pad): b128 reads conflict-free

// ---------------- K0: anchors ----------------
__global__ void anchor_kernel(float* __restrict__ out) {
  int i = blockIdx.x * 256 + threadIdx.x;
  if (i >= NANC) return;
  int s = i / 9, a = i - s * 9;
  int y = s >> 6, x = s & 63;
  int ri = a / 3, si = a - ri * 3;
  double r = (ri == 0) ? 0.5 : (ri == 1 ? 1.0 : 2.0);
  double sc = (si == 0) ? 8.0 : (si == 1 ? 16.0 : 32.0);
  double hh = 16.0 * sc * sqrt(r);
  double ww = 16.0 * sc * sqrt(1.0 / r);
  float a0 = (float)(8.0 - hh * 0.5);
  float a1 = (float)(8.0 - ww * 0.5);
  float a2 = (float)(8.0 + hh * 0.5);
  float a3 = (float)(8.0 + ww * 0.5);
  float sy = (float)(y * 16), sx = (float)(x * 16);
  out[OUT_ANC + i * 4 + 0] = a0 + sy;
  out[OUT_ANC + i * 4 + 1] = a1 + sx;
  out[OUT_ANC + i * 4 + 2] = a2 + sy;
  out[OUT_ANC + i * 4 + 3] = a3 + sx;
}

// ---------------- K0b: weight limb-split into B-fragment layout (unchanged) ----------------
__global__ void wprep_kernel(const float* __restrict__ w, _Float16* __restrict__ Bf) {
  int i = blockIdx.x * 256 + threadIdx.x;  // < 4718592
  int j = i & 7;
  int l = (i >> 3) & 63;
  int limb = (i >> 9) & 1;
  int ob = (i >> 10) & 31;
  int icb = (i >> 15) & 15;
  int tap = i >> 19;
  int ic = icb * 32 + ((l >> 4) << 3) + j;
  int oc = (ob << 4) + (l & 15);
  float v = w[((size_t)oc * CIN + ic) * 9 + tap] * WSCALE;
  _Float16 hi = (_Float16)v;
  Bf[i] = limb ? (_Float16)((v - (float)hi) * LSCALE) : hi;
}

// ---------------- K1: conv3x3 + bias + relu via MFMA (scaled f16 limbs) ----------------
// R18 == R12 compute, LOCKED (accumulation order + low-bit block mapping).
// blk0 split retained for tail visibility (~8us cost).
__global__ __launch_bounds__(256) void conv3_mfma(
    const float* __restrict__ x, const _Float16* __restrict__ Bf,
    const float* __restrict__ bias, float* __restrict__ h, int blk0) {
  __shared__ _Float16 xhi[2][108 * XS_STRIDE];  // 2 x 8640 B
  __shared__ _Float16 xlo[2][108 * XS_STRIDE];  // 2 x 8640 B
  int blk = blk0 + blockIdx.x;
  int ntblk = blk & 3;
  int mb = blk >> 2;
  int img = mb >> 6;
  int t = mb & 63;
  int ty0 = (t >> 2) * 4, tx0 = (t & 3) * 16;
  int tid = threadIdx.x;
  int wv = tid >> 6, lane = tid & 63;
  int col = lane & 15, quad = lane >> 4;

  f32x4 acc0[4][2], accC[4][2];
#pragma unroll
  for (int g = 0; g < 4; ++g)
#pragma unroll
    for (int nt = 0; nt < 2; ++nt) {
      acc0[g][nt] = (f32x4){0.f, 0.f, 0.f, 0.f};
      accC[g][nt] = (f32x4){0.f, 0.f, 0.f, 0.f};
    }

  int goffs[4];
  int laddr[4];
#pragma unroll
  for (int s = 0; s < 4; ++s) {
    int l = tid + (s << 8);
    bool act = (l < 864);
    int icg = l / 108;
    int pos = l - icg * 108;
    int py = pos / 18, px = pos - py * 18;
    int gy = ty0 - 1 + py, gx = tx0 - 1 + px;
    bool inb = act && ((unsigned)gy < 64u) && ((unsigned)gx < 64u);
    goffs[s] = inb ? ((icg << 14) + (gy << 6) + gx) : -1;
    laddr[s] = act ? (pos * XS_STRIDE + (icg << 2)) : -1;
  }

  const float* xn = x + ((size_t)img << 21);
  const half8* B8 = (const half8*)Bf;
  const half8* Bq = B8 + (((size_t)(ntblk * 8 + wv * 2)) << 7) + lane;
  int abase = col * XS_STRIDE + quad * 8;

  typedef _Float16 h4 __attribute__((ext_vector_type(4)));

  {
    const float* xb = xn;
#pragma unroll
    for (int s = 0; s < 4; ++s) {
      if (laddr[s] >= 0) {
        float v0 = 0.f, v1 = 0.f, v2 = 0.f, v3 = 0.f;
        if (goffs[s] >= 0) {
          const float* p = xb + goffs[s];
          v0 = p[0]; v1 = p[HW]; v2 = p[2 * HW]; v3 = p[3 * HW];
        }
        _Float16 h0 = (_Float16)v0, h1 = (_Float16)v1;
        _Float16 h2 = (_Float16)v2, h3 = (_Float16)v3;
        _Float16 e0 = (_Float16)((v0 - (float)h0) * LSCALE);
        _Float16 e1 = (_Float16)((v1 - (float)h1) * LSCALE);
        _Float16 e2 = (_Float16)((v2 - (float)h2) * LSCALE);
        _Float16 e3 = (_Float16)((v3 - (float)h3) * LSCALE);
        *(h4*)(xhi[0] + laddr[s]) = (h4){h0, h1, h2, h3};
        *(h4*)(xlo[0] + laddr[s]) = (h4){e0, e1, e2, e3};
      }
    }
  }
  __syncthreads();

#pragma unroll 1
  for (int icb = 0; icb < 16; ++icb) {
    int cur = icb & 1;
    float pv0[4], pv1[4], pv2[4], pv3[4];
    const int nxt = icb + 1;
    if (nxt < 16) {
      const float* xb = xn + ((size_t)nxt << 17);
#pragma unroll
      for (int s = 0; s < 4; ++s) {
        pv0[s] = 0.f; pv1[s] = 0.f; pv2[s] = 0.f; pv3[s] = 0.f;
        if (goffs[s] >= 0) {
          const float* p = xb + goffs[s];
          pv0[s] = p[0]; pv1[s] = p[HW]; pv2[s] = p[2 * HW]; pv3[s] = p[3 * HW];
        }
      }
    }
    const _Float16* xh = xhi[cur];
    const _Float16* xl = xlo[cur];
    __builtin_amdgcn_s_setprio(1);
#pragma unroll
    for (int ky = 0; ky < 3; ++ky) {
#pragma unroll
      for (int kx = 0; kx < 3; ++kx) {
        int tap = ky * 3 + kx;
        size_t boff = ((size_t)(tap * 16 + icb)) << 12;
        half8 Bh0 = Bq[boff];
        half8 Bl0 = Bq[boff + 64];
        half8 Bh1 = Bq[boff + 128];
        half8 Bl1 = Bq[boff + 192];
        int toff = (ky * 18 + kx) * XS_STRIDE + abase;
#pragma unroll
        for (int g = 0; g < 4; ++g) {
          int off = toff + g * (18 * XS_STRIDE);
          half8 Ah = *(const half8*)(xh + off);
          half8 Al = *(const half8*)(xl + off);
          acc0[g][0] = __builtin_amdgcn_mfma_f32_16x16x32_f16(Ah, Bh0, acc0[g][0], 0, 0, 0);
          accC[g][0] = __builtin_amdgcn_mfma_f32_16x16x32_f16(Ah, Bl0, accC[g][0], 0, 0, 0);
          accC[g][0] = __builtin_amdgcn_mfma_f32_16x16x32_f16(Al, Bh0, accC[g][0], 0, 0, 0);
          acc0[g][1] = __builtin_amdgcn_mfma_f32_16x16x32_f16(Ah, Bh1, acc0[g][1], 0, 0, 0);
          accC[g][1] = __builtin_amdgcn_mfma_f32_16x16x32_f16(Ah, Bl1, accC[g][1], 0, 0, 0);
          accC[g][1] = __builtin_amdgcn_mfma_f32_16x16x32_f16(Al, Bh1, accC[g][1], 0, 0, 0);
        }
      }
    }
    __builtin_amdgcn_s_setprio(0);
    if (nxt < 16) {
      _Float16* wh = xhi[cur ^ 1];
      _Float16* wl = xlo[cur ^ 1];
#pragma unroll
      for (int s = 0; s < 4; ++s) {
        if (laddr[s] >= 0) {
          float v0 = pv0[s], v1 = pv1[s], v2 = pv2[s], v3 = pv3[s];
          _Float16 h0 = (_Float16)v0, h1 = (_Float16)v1;
          _Float16 h2 = (_Float16)v2, h3 = (_Float16)v3;
          _Float16 e0 = (_Float16)((v0 - (float)h0) * LSCALE);
          _Float16 e1 = (_Float16)((v1 - (float)h1) * LSCALE);
          _Float16 e2 = (_Float16)((v2 - (float)h2) * LSCALE);
          _Float16 e3 = (_Float16)((v3 - (float)h3) * LSCALE);
          *(h4*)(wh + laddr[s]) = (h4){h0, h1, h2, h3};
          *(h4*)(wl + laddr[s]) = (h4){e0, e1, e2, e3};
        }
      }
    }
    __syncthreads();
  }
#pragma unroll
  for (int g = 0; g < 4; ++g) {
#pragma unroll
    for (int nt = 0; nt < 2; ++nt) {
      int oc = (ntblk << 7) + (wv << 5) + (nt << 4) + col;
      float bv = bias[oc];
      int gy = ty0 + g;
      int gx0 = tx0 + (quad << 2);
      f32x4 a0 = acc0[g][nt];
      f32x4 ac = accC[g][nt];
      float4 o;
      o.x = fmaf(ac.x, INV_LS, a0.x) * INV_WS + bv; o.x = o.x > 0.f ? o.x : 0.f;
      o.y = fmaf(ac.y, INV_LS, a0.y) * INV_WS + bv; o.y = o.y > 0.f ? o.y : 0.f;
      o.z = fmaf(ac.z, INV_LS, a0.z) * INV_WS + bv; o.z = o.z > 0.f ? o.z : 0.f;
      o.w = fmaf(ac.w, INV_LS, a0.w) * INV_WS + bv; o.w = o.w > 0.f ? o.w : 0.f;
      *(float4*)(h + ((size_t)img * CIN + oc) * HW + (gy << 6) + gx0) = o;
    }
  }
}

// ---------------- K2a: 1x1 heads matmul, k-SPLIT across blocks (R16, kept) ----------------
__global__ __launch_bounds__(256) void heads_mm(
    const float* __restrict__ h, const float* __restrict__ sw,
    const float* __restrict__ lw, float* __restrict__ hacc) {
  __shared__ float wlds[512][20];  // 40960 B (pad 18->20: 80B rows, 16B-aligned)
  __shared__ float part[128][20];  // 10240 B
  int tid = threadIdx.x;
  int sl = tid >> 7;
  int pl = tid & 127;
  int blk = blockIdx.x;
  int kg = blk >> 8;        // 0..2
  int rem = blk & 255;
  int n = rem >> 5;
  int s0 = (rem & 31) * 128;

  const float* wsrc = (kg == 0) ? sw : (lw + (size_t)(kg == 1 ? 0 : 18) * CIN);
  for (int l = tid; l < 18 * 512; l += 256) {
    int j = l >> 9;       // 0..17 (k within group)
    int c = l & 511;      // coalesced global read
    wlds[c][j] = wsrc[(size_t)j * CIN + c];
  }
  __syncthreads();

  float acc[18];
#pragma unroll
  for (int j = 0; j < 18; ++j) acc[j] = 0.f;
  int cb = sl * 256;
  const float* hp = h + ((size_t)n * CIN + cb) * HW + s0 + pl;
#pragma unroll 4
  for (int cl = 0; cl < 256; ++cl) {
    float hv = hp[(size_t)cl * HW];
    const float* wr = &wlds[cb + cl][0];  // wave-uniform address -> broadcast
    float4 wa = *(const float4*)(wr + 0);
    float4 wb = *(const float4*)(wr + 4);
    float4 wc = *(const float4*)(wr + 8);
    float4 wd = *(const float4*)(wr + 12);
    float2 we = *(const float2*)(wr + 16);
    acc[0]  = fmaf(hv, wa.x, acc[0]);  acc[1]  = fmaf(hv, wa.y, acc[1]);
    acc[2]  = fmaf(hv, wa.z, acc[2]);  acc[3]  = fmaf(hv, wa.w, acc[3]);
    acc[4]  = fmaf(hv, wb.x, acc[4]);  acc[5]  = fmaf(hv, wb.y, acc[5]);
    acc[6]  = fmaf(hv, wb.z, acc[6]);  acc[7]  = fmaf(hv, wb.w, acc[7]);
    acc[8]  = fmaf(hv, wc.x, acc[8]);  acc[9]  = fmaf(hv, wc.y, acc[9]);
    acc[10] = fmaf(hv, wc.z, acc[10]); acc[11] = fmaf(hv, wc.w, acc[11]);
    acc[12] = fmaf(hv, wd.x, acc[12]); acc[13] = fmaf(hv, wd.y, acc[13]);
    acc[14] = fmaf(hv, wd.z, acc[14]); acc[15] = fmaf(hv, wd.w, acc[15]);
    acc[16] = fmaf(hv, we.x, acc[16]); acc[17] = fmaf(hv, we.y, acc[17]);
  }
  if (sl == 1) {
#pragma unroll
    for (int j = 0; j < 18; ++j) part[pl][j] = acc[j];
  }
  __syncthreads();
  if (sl == 0) {
    int s = s0 + pl;
#pragma unroll
    for (int j = 0; j < 18; ++j) {
      float v = acc[j] + part[pl][j];  // sl0-chain + sl1-chain (order as before)
      hacc[(size_t)(kg * 18 + j) * (NB * HW) + (size_t)n * HW + s] = v;
    }
  }
}

// ---------------- K2b: heads epilogue (verbatim arithmetic) ----------------
__global__ __launch_bounds__(256) void heads_epi(
    const float* __restrict__ hacc, const float* __restrict__ sb,
    const float* __restrict__ lb, float* __restrict__ out,
    float* __restrict__ fgm, float* __restrict__ boxes) {
  int g = blockIdx.x * 256 + threadIdx.x;  // 0..32767
  int n = g >> 12;
  int s = g & 4095;
  float acc[54];
#pragma unroll
  for (int k = 0; k < 54; ++k)
    acc[k] = hacc[(size_t)k * (NB * HW) + (size_t)n * HW + s];
  int y = s >> 6, xx = s & 63;
  float sc[18], lo[36];
#pragma unroll
  for (int k = 0; k < 18; k++) sc[k] = acc[k] + sb[k];
#pragma unroll
  for (int k = 0; k < 36; k++) lo[k] = acc[18 + k] + lb[k];
  size_t base = (size_t)n * NANC + (size_t)s * 9;
#pragma unroll
  for (int i = 0; i < 36; i++) out[OUT_LOCS + base * 4 + i] = lo[i];
#pragma unroll
  for (int i = 0; i < 18; i++) out[OUT_SCORES + base * 2 + i] = sc[i];
  float syf = (float)(y * 16), sxf = (float)(xx * 16);
#pragma unroll
  for (int a = 0; a < 9; a++) {
    float s0v = sc[a * 2], s1v = sc[a * 2 + 1];
    float m = fmaxf(s0v, s1v);
    float e0 = expf(s0v - m), e1 = expf(s1v - m);
    float fg = e1 / (e0 + e1);
    int ri = a / 3, si = a - ri * 3;
    double r = (ri == 0) ? 0.5 : (ri == 1 ? 1.0 : 2.0);
    double scd = (si == 0) ? 8.0 : (si == 1 ? 16.0 : 32.0);
    double hhd = 16.0 * scd * sqrt(r);
    double wwd = 16.0 * scd * sqrt(1.0 / r);
    float a0 = (float)(8.0 - hhd * 0.5) + syf;
    float a1 = (float)(8.0 - wwd * 0.5) + sxf;
    float a2 = (float)(8.0 + hhd * 0.5) + syf;
    float a3 = (float)(8.0 + wwd * 0.5) + sxf;
    float hA = a2 - a0, wA = a3 - a1;
    float cy = a0 + 0.5f * hA, cx = a1 + 0.5f * wA;
    float dy = lo[a * 4 + 0], dx = lo[a * 4 + 1];
    float dh = lo[a * 4 + 2], dw = lo[a * 4 + 3];
    float cy2 = dy * hA + cy, cx2 = dx * wA + cx;
    float h2 = expf(dh) * hA, w2 = expf(dw) * wA;
    float b0 = cy2 - 0.5f * h2, b1 = cx2 - 0.5f * w2;
    float b2 = cy2 + 0.5f * h2, b3 = cx2 + 0.5f * w2;
    b0 = fminf(fmaxf(b0, 0.f), 1024.f);
    b1 = fminf(fmaxf(b1, 0.f), 1024.f);
    b2 = fminf(fmaxf(b2, 0.f), 1024.f);
    b3 = fminf(fmaxf(b3, 0.f), 1024.f);
    float hs = b2 - b0, wss = b3 - b1;
    bool valid = (hs >= 16.f) && (wss >= 16.f);
    size_t bi = base + a;
    boxes[bi * 4 + 0] = b0; boxes[bi * 4 + 1] = b1;
    boxes[bi * 4 + 2] = b2; boxes[bi * 4 + 3] = b3;
    fgm[bi] = valid ? fg : -__builtin_inff();
  }
}

// ---------------- K3: top-2000 (4-pass radix on 32-bit orderable score) ----------------
__device__ __forceinline__ uint32_t ord32(float v) {
  uint32_t s = __float_as_uint(v);
  return (s & 0x80000000u) ? ~s : (s | 0x80000000u);
}

__global__ __launch_bounds__(1024) void select2_kernel(
    const float* __restrict__ fgm, const float* __restrict__ boxes,
    float4* __restrict__ selb, uint8_t* __restrict__ selv) {
  int n = blockIdx.x;
  const float* f = fgm + (size_t)n * NANC;
  __shared__ uint32_t hist[256];
  __shared__ uint32_t segsum[16], segsufE[16];
  __shared__ uint64_t keys[2048];
  __shared__ uint32_t sh_digit, sh_T, scnt;
  int tid = threadIdx.x;
  uint32_t pref = 0;
  uint32_t T = PRE;
  for (int p = 0; p < 4; ++p) {
    int shift = 24 - 8 * p;
    if (tid < 256) hist[tid] = 0;
    __syncthreads();
    for (int i = tid; i < NANC; i += 1024) {
      uint32_t u = ord32(f[i]);
      bool match = (p == 0) || ((u >> (shift + 8)) == (pref >> (shift + 8)));
      if (match) atomicAdd(&hist[(u >> shift) & 255u], 1u);
    }
    __syncthreads();
    if (tid < 16) {
      uint32_t s = 0;
      for (int j = 0; j < 16; ++j) s += hist[tid * 16 + j];
      segsum[tid] = s;
    }
    __syncthreads();
    if (tid == 0) {
      uint32_t run = 0;
      for (int s = 15; s >= 0; --s) { segsufE[s] = run; run += segsum[s]; }
    }
    __syncthreads();
    if (tid < 256) {
      int d = tid, s = d >> 4;
      uint32_t loc = 0;
      for (int j = d; j < (s + 1) * 16; ++j) loc += hist[j];
      uint32_t suf = segsufE[s] + loc;
      uint32_t sufn = suf - hist[d];
      if (suf >= T && sufn < T) { sh_digit = (uint32_t)d; sh_T = T - sufn; }
    }
    __syncthreads();
    pref |= sh_digit << shift;
    T = sh_T;
    __syncthreads();
  }
  if (tid == 0) scnt = 0;
  __syncthreads();
  for (int i = tid; i < NANC; i += 1024) {
    uint32_t u = ord32(f[i]);
    if (u >= pref) {
      uint32_t pos = atomicAdd(&scnt, 1u);
      if (pos < 2048) keys[pos] = ((uint64_t)u << 32) | (uint32_t)(~(uint32_t)i);
    }
  }
  __syncthreads();
  uint32_t sc = scnt > 2048 ? 2048 : scnt;
  for (int i = sc + tid; i < 2048; i += 1024) keys[i] = 0;
  __syncthreads();
  for (int k = 2; k <= 2048; k <<= 1) {
    for (int j = k >> 1; j > 0; j >>= 1) {
      for (int e = tid; e < 2048; e += 1024) {
        int partner = e ^ j;
        if (partner > e) {
          bool up = ((e & k) == 0);
          uint64_t a = keys[e], b = keys[partner];
          if (up ? (a < b) : (a > b)) { keys[e] = b; keys[partner] = a; }
        }
      }
      __syncthreads();
    }
  }
  for (int t2 = tid; t2 < PRE; t2 += 1024) {
    uint64_t key = keys[t2];
    uint32_t idx = ~((uint32_t)(key & 0xFFFFFFFFu));
    const float4* bp = (const float4*)(boxes + ((size_t)n * NANC + idx) * 4);
    selb[(size_t)n * 2048 + t2] = *bp;
    selv[(size_t)n * 2048 + t2] = ((uint32_t)(key >> 32)) > 0x007FFFFFu ? 1 : 0;
  }
}

// ---------------- K4a: NMS suppression mask (grid-parallel) ----------------
__global__ __launch_bounds__(256) void nms_mask_kernel(
    const float4* __restrict__ selb, uint64_t* __restrict__ mask) {
  __shared__ float by0[PRE], bx0_[PRE], by1[PRE], bx1_[PRE], bar[PRE];
  int b = blockIdx.x;
  int n = b / 250;
  int i0 = (b % 250) * 8;
  int tid = threadIdx.x;
  for (int j = tid; j < PRE; j += 256) {
    float4 bb = selb[(size_t)n * 2048 + j];
    by0[j] = bb.x; bx0_[j] = bb.y; by1[j] = bb.z; bx1_[j] = bb.w;
    bar[j] = (bb.z - bb.x) * (bb.w - bb.y);
  }
  __syncthreads();
  int i = i0 + (tid >> 5);
  int jw = tid & 31;
  float iy0 = by0[i], ix0 = bx0_[i], iy1 = by1[i], ix1 = bx1_[i], ia = bar[i];
  uint64_t bits = 0;
  int jb = jw * 64;
  for (int tb = 0; tb < 64; ++tb) {
    int tbp = (tb + jw) & 63;
    int j = jb + tbp;
    if (j < PRE && j > i) {
      float ty = fmaxf(iy0, by0[j]);
      float txx = fmaxf(ix0, bx0_[j]);
      float byv = fminf(iy1, by1[j]);
      float bxv = fminf(ix1, bx1_[j]);
      float ih = byv - ty; if (ih < 0.f) ih = 0.f;
      float iw = bxv - txx; if (iw < 0.f) iw = 0.f;
      float inter = ih * iw;
      float iou = inter / (ia + bar[j] - inter + 1e-9f);
      if (iou > 0.7f) bits |= (1ull << tbp);
    }
  }
  mask[((size_t)n * PRE + i) * 32 + jw] = bits;
}

// ---------------- K4b: NMS bit-scan, SPECULATIVE BATCH jump-scan (R18) ----------------
// R18: R17's jump-scan was latency-bound at MLP=1 (~300 iter x ~1100cyc
// dependent round-trips = 137us). Mask rows are STATIC data: only the
// apply-decision depends on kw. So per batch: extract up to 8 candidate
// indices from CURRENT kw (VALU-only ballot/ffs on a temp copy), issue all 8
// row-loads back-to-back (MLP=8, ~one latency), then apply sequentially with
// a re-check of each candidate against the updated kw. kw only loses bits ->
// candidates are a superset of the true next-kept sequence; re-check keeps
// the greedy order EXACT (skipped candidates = rows the original also never
// applied; POST-th row not applied, same as R17, masked by km). rr[]/cand[]
// fully unrolled, compile-time indices -> registers. Bit-identical output.
__global__ __launch_bounds__(64) void nms_scan_kernel(
    const uint8_t* __restrict__ selv, const uint64_t* __restrict__ mask,
    const float4* __restrict__ selb, float* __restrict__ out) {
  int n = blockIdx.x;
  int lane = threadIdx.x;
  const uint8_t* sv = selv + (size_t)n * 2048;
  uint64_t kw = 0;
  for (int wblk = 0; wblk < 32; ++wblk) {
    int j = wblk * 64 + lane;
    bool pred = (j < PRE) && (sv[j] != 0);
    uint64_t m = __ballot(pred);
    if (lane == wblk) kw = m;
  }
  const uint64_t* mrow = mask + (size_t)n * PRE * 32;
  int istar = PRE - 1;
  int csf = 0;
  int ip = -1;  // last examined index
  bool done = false;
  while (!done) {
    // ---- extract up to 8 candidates (> ip) from current kw; issue loads ----
    int nb = ip + 1;
    int cw = nb >> 6, cb = nb & 63;
    uint64_t eff = kw;  // lanes >= 32 hold 0
    if (lane < cw) eff = 0;
    if (lane == cw && cb) eff &= ~((1ull << cb) - 1ull);
    int cand[8];
    uint64_t rr[8];
#pragma unroll
    for (int b = 0; b < 8; ++b) {
      uint64_t nz = __ballot(eff != 0ull);
      int c = -1;
      if (nz != 0ull) {
        int lw = __ffsll((unsigned long long)nz) - 1;
        uint64_t wvv = __shfl(eff, lw);
        int ibit = __ffsll((unsigned long long)wvv) - 1;
        c = lw * 64 + ibit;
        if (lane == lw) eff &= ~(1ull << ibit);
      }
      cand[b] = c;
      rr[b] = (c >= 0 && lane < 32) ? mrow[(size_t)c * 32 + lane] : 0ull;
    }
    if (cand[0] < 0) break;  // no kept boxes remain
    // ---- apply sequentially with re-check against updated kw ----
#pragma unroll
    for (int b = 0; b < 8; ++b) {
      int c = cand[b];
      if (!done && c >= 0) {
        uint64_t w = __shfl(kw, c >> 6);
        if ((w >> (c & 63)) & 1ull) {       // still kept under updated kw
          csf++;
          if (csf >= POST) { istar = c; done = true; }
          else kw &= ~rr[b];
        }
        ip = c;
      }
    }
  }
  // mask off indices beyond istar
  int wordi = istar >> 6, biti = istar & 63;
  uint64_t km = (lane < wordi) ? ~0ull
              : (lane == wordi ? ((biti == 63) ? ~0ull : ((1ull << (biti + 1)) - 1ull)) : 0ull);
  uint64_t kwv = (lane < 32) ? (kw & km) : 0ull;
  int pc = __popcll(kwv);
  int pre = pc;
  for (int d = 1; d < 64; d <<= 1) {
    int v = __shfl_up(pre, d);
    if (lane >= d) pre += v;
  }
  int total = __shfl(pre, 63);
  int rank = pre - pc;
  uint64_t bits = kwv;
  while (bits) {
    int bpos = __ffsll((unsigned long long)bits) - 1;
    bits &= bits - 1;
    if (rank < POST) {
      int j = lane * 64 + bpos;
      float4 bx = selb[(size_t)n * 2048 + j];
      size_t o = (size_t)OUT_ROIS + ((size_t)n * POST + rank) * 4;
      out[o + 0] = bx.x; out[o + 1] = bx.y; out[o + 2] = bx.z; out[o + 3] = bx.w;
    }
    rank++;
  }
  int cnt = total > POST ? POST : total;
  for (int r2 = cnt + lane; r2 < POST; r2 += 64) {
    size_t o = (size_t)OUT_ROIS + ((size_t)n * POST + r2) * 4;
    out[o + 0] = 0.f; out[o + 1] = 0.f; out[o + 2] = 0.f; out[o + 3] = 0.f;
  }
  for (int r2 = lane; r2 < POST; r2 += 64)
    out[OUT_RIDX + n * POST + r2] = (float)n;
}

extern "C" void kernel_launch(void* const* d_in, const int* in_sizes, int n_in,
                              void* d_out, int out_size, void* d_ws, size_t ws_size,
                              hipStream_t stream) {
  const float* x   = (const float*)d_in[0];
  const float* c1w = (const float*)d_in[1];
  const float* c1b = (const float*)d_in[2];
  const float* sw  = (const float*)d_in[3];
  const float* sb  = (const float*)d_in[4];
  const float* lw  = (const float*)d_in[5];
  const float* lb  = (const float*)d_in[6];
  float* out = (float*)d_out;
  char* ws = (char*)d_ws;
  float*     hbuf = (float*)(ws);                        // 67,108,864 B
  float*     fgm  = (float*)(ws + 67108864);             // 1,179,648 B
  float*     boxes= (float*)(ws + 68288512);             // 4,718,592 B
  _Float16*  Bf   = (_Float16*)(ws + 73007104);          // 9,437,184 B
  float*     hacc = (float*)(ws + 73007104);             // aliases Bf: conv done before heads_mm (stream-ordered); 7,077,888 B <= 9,437,184 B
  float4*    selb = (float4*)(ws + 82444288);            // 262,144 B
  uint8_t*   selv = (uint8_t*)(ws + 82706432);           // 16,384 B
  uint64_t*  mask = (uint64_t*)(ws + 82722816);          // 4,096,000 B

  anchor_kernel<<<144, 256, 0, stream>>>(out);
  wprep_kernel<<<18432, 256, 0, stream>>>(c1w, Bf);
  // diagnostic 4-way split: bit-identical to one 2048-block dispatch
  conv3_mfma<<<512, 256, 0, stream>>>(x, Bf, c1b, hbuf, 0);
  conv3_mfma<<<512, 256, 0, stream>>>(x, Bf, c1b, hbuf, 512);
  conv3_mfma<<<512, 256, 0, stream>>>(x, Bf, c1b, hbuf, 1024);
  conv3_mfma<<<512, 256, 0, stream>>>(x, Bf, c1b, hbuf, 1536);
  heads_mm<<<768, 256, 0, stream>>>(hbuf, sw, lw, hacc);
  heads_epi<<<128, 256, 0, stream>>>(hacc, sb, lb, out, fgm, boxes);
  select2_kernel<<<8, 1024, 0, stream>>>(fgm, boxes, selb, selv);
  nms_mask_kernel<<<2000, 256, 0, stream>>>(selb, mask);
  nms_scan_kernel<<<8, 64, 0, stream>>>(selv, mask, selb, out);
}

// Round 11
// 780.468 us; speedup vs baseline: 1.0964x; 1.0964x over previous
//
#include <hip/hip_runtime.h>
#include <math.h>
#include <stdint.h>

#define NB 8
#define CIN 512
#define HW 4096
#define ANUM 9
#define NANC 36864
#define PRE 2000
#define POST 300

// d_out float offsets
#define OUT_LOCS   0
#define OUT_SCORES 1179648
#define OUT_ROIS   1769472
#define OUT_RIDX   1779072
#define OUT_ANC    1781472

typedef _Float16 half8 __attribute__((ext_vector_type(8)));
typedef float f32x4 __attribute__((ext_vector_type(4)));

#define WSCALE 256.0f
#define LSCALE 4096.0f
#define INV_WS (1.0f / 256.0f)
#define INV_LS (1.0f / 4096.0f)
#define XS_STRIDE 40  // halfs per halo position (32 data + 8 pad): b128 reads conflict-free

// ---------------- K0: anchors ----------------
__global__ void anchor_kernel(float* __restrict__ out) {
  int i = blockIdx.x * 256 + threadIdx.x;
  if (i >= NANC) return;
  int s = i / 9, a = i - s * 9;
  int y = s >> 6, x = s & 63;
  int ri = a / 3, si = a - ri * 3;
  double r = (ri == 0) ? 0.5 : (ri == 1 ? 1.0 : 2.0);
  double sc = (si == 0) ? 8.0 : (si == 1 ? 16.0 : 32.0);
  double hh = 16.0 * sc * sqrt(r);
  double ww = 16.0 * sc * sqrt(1.0 / r);
  float a0 = (float)(8.0 - hh * 0.5);
  float a1 = (float)(8.0 - ww * 0.5);
  float a2 = (float)(8.0 + hh * 0.5);
  float a3 = (float)(8.0 + ww * 0.5);
  float sy = (float)(y * 16), sx = (float)(x * 16);
  out[OUT_ANC + i * 4 + 0] = a0 + sy;
  out[OUT_ANC + i * 4 + 1] = a1 + sx;
  out[OUT_ANC + i * 4 + 2] = a2 + sy;
  out[OUT_ANC + i * 4 + 3] = a3 + sx;
}

// ---------------- K0b: weight limb-split into B-fragment layout (unchanged) ----------------
__global__ void wprep_kernel(const float* __restrict__ w, _Float16* __restrict__ Bf) {
  int i = blockIdx.x * 256 + threadIdx.x;  // < 4718592
  int j = i & 7;
  int l = (i >> 3) & 63;
  int limb = (i >> 9) & 1;
  int ob = (i >> 10) & 31;
  int icb = (i >> 15) & 15;
  int tap = i >> 19;
  int ic = icb * 32 + ((l >> 4) << 3) + j;
  int oc = (ob << 4) + (l & 15);
  float v = w[((size_t)oc * CIN + ic) * 9 + tap] * WSCALE;
  _Float16 hi = (_Float16)v;
  Bf[i] = limb ? (_Float16)((v - (float)hi) * LSCALE) : hi;
}

// ---------------- K1: conv3x3 + bias + relu via MFMA (scaled f16 limbs) ----------------
// R19 == R12 compute, LOCKED (accumulation order + low-bit block mapping).
// blk0 split retained for tail visibility (~8us cost).
__global__ __launch_bounds__(256) void conv3_mfma(
    const float* __restrict__ x, const _Float16* __restrict__ Bf,
    const float* __restrict__ bias, float* __restrict__ h, int blk0) {
  __shared__ _Float16 xhi[2][108 * XS_STRIDE];  // 2 x 8640 B
  __shared__ _Float16 xlo[2][108 * XS_STRIDE];  // 2 x 8640 B
  int blk = blk0 + blockIdx.x;
  int ntblk = blk & 3;
  int mb = blk >> 2;
  int img = mb >> 6;
  int t = mb & 63;
  int ty0 = (t >> 2) * 4, tx0 = (t & 3) * 16;
  int tid = threadIdx.x;
  int wv = tid >> 6, lane = tid & 63;
  int col = lane & 15, quad = lane >> 4;

  f32x4 acc0[4][2], accC[4][2];
#pragma unroll
  for (int g = 0; g < 4; ++g)
#pragma unroll
    for (int nt = 0; nt < 2; ++nt) {
      acc0[g][nt] = (f32x4){0.f, 0.f, 0.f, 0.f};
      accC[g][nt] = (f32x4){0.f, 0.f, 0.f, 0.f};
    }

  int goffs[4];
  int laddr[4];
#pragma unroll
  for (int s = 0; s < 4; ++s) {
    int l = tid + (s << 8);
    bool act = (l < 864);
    int icg = l / 108;
    int pos = l - icg * 108;
    int py = pos / 18, px = pos - py * 18;
    int gy = ty0 - 1 + py, gx = tx0 - 1 + px;
    bool inb = act && ((unsigned)gy < 64u) && ((unsigned)gx < 64u);
    goffs[s] = inb ? ((icg << 14) + (gy << 6) + gx) : -1;
    laddr[s] = act ? (pos * XS_STRIDE + (icg << 2)) : -1;
  }

  const float* xn = x + ((size_t)img << 21);
  const half8* B8 = (const half8*)Bf;
  const half8* Bq = B8 + (((size_t)(ntblk * 8 + wv * 2)) << 7) + lane;
  int abase = col * XS_STRIDE + quad * 8;

  typedef _Float16 h4 __attribute__((ext_vector_type(4)));

  {
    const float* xb = xn;
#pragma unroll
    for (int s = 0; s < 4; ++s) {
      if (laddr[s] >= 0) {
        float v0 = 0.f, v1 = 0.f, v2 = 0.f, v3 = 0.f;
        if (goffs[s] >= 0) {
          const float* p = xb + goffs[s];
          v0 = p[0]; v1 = p[HW]; v2 = p[2 * HW]; v3 = p[3 * HW];
        }
        _Float16 h0 = (_Float16)v0, h1 = (_Float16)v1;
        _Float16 h2 = (_Float16)v2, h3 = (_Float16)v3;
        _Float16 e0 = (_Float16)((v0 - (float)h0) * LSCALE);
        _Float16 e1 = (_Float16)((v1 - (float)h1) * LSCALE);
        _Float16 e2 = (_Float16)((v2 - (float)h2) * LSCALE);
        _Float16 e3 = (_Float16)((v3 - (float)h3) * LSCALE);
        *(h4*)(xhi[0] + laddr[s]) = (h4){h0, h1, h2, h3};
        *(h4*)(xlo[0] + laddr[s]) = (h4){e0, e1, e2, e3};
      }
    }
  }
  __syncthreads();

#pragma unroll 1
  for (int icb = 0; icb < 16; ++icb) {
    int cur = icb & 1;
    float pv0[4], pv1[4], pv2[4], pv3[4];
    const int nxt = icb + 1;
    if (nxt < 16) {
      const float* xb = xn + ((size_t)nxt << 17);
#pragma unroll
      for (int s = 0; s < 4; ++s) {
        pv0[s] = 0.f; pv1[s] = 0.f; pv2[s] = 0.f; pv3[s] = 0.f;
        if (goffs[s] >= 0) {
          const float* p = xb + goffs[s];
          pv0[s] = p[0]; pv1[s] = p[HW]; pv2[s] = p[2 * HW]; pv3[s] = p[3 * HW];
        }
      }
    }
    const _Float16* xh = xhi[cur];
    const _Float16* xl = xlo[cur];
    __builtin_amdgcn_s_setprio(1);
#pragma unroll
    for (int ky = 0; ky < 3; ++ky) {
#pragma unroll
      for (int kx = 0; kx < 3; ++kx) {
        int tap = ky * 3 + kx;
        size_t boff = ((size_t)(tap * 16 + icb)) << 12;
        half8 Bh0 = Bq[boff];
        half8 Bl0 = Bq[boff + 64];
        half8 Bh1 = Bq[boff + 128];
        half8 Bl1 = Bq[boff + 192];
        int toff = (ky * 18 + kx) * XS_STRIDE + abase;
#pragma unroll
        for (int g = 0; g < 4; ++g) {
          int off = toff + g * (18 * XS_STRIDE);
          half8 Ah = *(const half8*)(xh + off);
          half8 Al = *(const half8*)(xl + off);
          acc0[g][0] = __builtin_amdgcn_mfma_f32_16x16x32_f16(Ah, Bh0, acc0[g][0], 0, 0, 0);
          accC[g][0] = __builtin_amdgcn_mfma_f32_16x16x32_f16(Ah, Bl0, accC[g][0], 0, 0, 0);
          accC[g][0] = __builtin_amdgcn_mfma_f32_16x16x32_f16(Al, Bh0, accC[g][0], 0, 0, 0);
          acc0[g][1] = __builtin_amdgcn_mfma_f32_16x16x32_f16(Ah, Bh1, acc0[g][1], 0, 0, 0);
          accC[g][1] = __builtin_amdgcn_mfma_f32_16x16x32_f16(Ah, Bl1, accC[g][1], 0, 0, 0);
          accC[g][1] = __builtin_amdgcn_mfma_f32_16x16x32_f16(Al, Bh1, accC[g][1], 0, 0, 0);
        }
      }
    }
    __builtin_amdgcn_s_setprio(0);
    if (nxt < 16) {
      _Float16* wh = xhi[cur ^ 1];
      _Float16* wl = xlo[cur ^ 1];
#pragma unroll
      for (int s = 0; s < 4; ++s) {
        if (laddr[s] >= 0) {
          float v0 = pv0[s], v1 = pv1[s], v2 = pv2[s], v3 = pv3[s];
          _Float16 h0 = (_Float16)v0, h1 = (_Float16)v1;
          _Float16 h2 = (_Float16)v2, h3 = (_Float16)v3;
          _Float16 e0 = (_Float16)((v0 - (float)h0) * LSCALE);
          _Float16 e1 = (_Float16)((v1 - (float)h1) * LSCALE);
          _Float16 e2 = (_Float16)((v2 - (float)h2) * LSCALE);
          _Float16 e3 = (_Float16)((v3 - (float)h3) * LSCALE);
          *(h4*)(wh + laddr[s]) = (h4){h0, h1, h2, h3};
          *(h4*)(wl + laddr[s]) = (h4){e0, e1, e2, e3};
        }
      }
    }
    __syncthreads();
  }
#pragma unroll
  for (int g = 0; g < 4; ++g) {
#pragma unroll
    for (int nt = 0; nt < 2; ++nt) {
      int oc = (ntblk << 7) + (wv << 5) + (nt << 4) + col;
      float bv = bias[oc];
      int gy = ty0 + g;
      int gx0 = tx0 + (quad << 2);
      f32x4 a0 = acc0[g][nt];
      f32x4 ac = accC[g][nt];
      float4 o;
      o.x = fmaf(ac.x, INV_LS, a0.x) * INV_WS + bv; o.x = o.x > 0.f ? o.x : 0.f;
      o.y = fmaf(ac.y, INV_LS, a0.y) * INV_WS + bv; o.y = o.y > 0.f ? o.y : 0.f;
      o.z = fmaf(ac.z, INV_LS, a0.z) * INV_WS + bv; o.z = o.z > 0.f ? o.z : 0.f;
      o.w = fmaf(ac.w, INV_LS, a0.w) * INV_WS + bv; o.w = o.w > 0.f ? o.w : 0.f;
      *(float4*)(h + ((size_t)img * CIN + oc) * HW + (gy << 6) + gx0) = o;
    }
  }
}

// ---------------- K2a: 1x1 heads matmul, k-SPLIT across blocks (R16, kept) ----------------
__global__ __launch_bounds__(256) void heads_mm(
    const float* __restrict__ h, const float* __restrict__ sw,
    const float* __restrict__ lw, float* __restrict__ hacc) {
  __shared__ float wlds[512][20];  // 40960 B (pad 18->20: 80B rows, 16B-aligned)
  __shared__ float part[128][20];  // 10240 B
  int tid = threadIdx.x;
  int sl = tid >> 7;
  int pl = tid & 127;
  int blk = blockIdx.x;
  int kg = blk >> 8;        // 0..2
  int rem = blk & 255;
  int n = rem >> 5;
  int s0 = (rem & 31) * 128;

  const float* wsrc = (kg == 0) ? sw : (lw + (size_t)(kg == 1 ? 0 : 18) * CIN);
  for (int l = tid; l < 18 * 512; l += 256) {
    int j = l >> 9;       // 0..17 (k within group)
    int c = l & 511;      // coalesced global read
    wlds[c][j] = wsrc[(size_t)j * CIN + c];
  }
  __syncthreads();

  float acc[18];
#pragma unroll
  for (int j = 0; j < 18; ++j) acc[j] = 0.f;
  int cb = sl * 256;
  const float* hp = h + ((size_t)n * CIN + cb) * HW + s0 + pl;
#pragma unroll 4
  for (int cl = 0; cl < 256; ++cl) {
    float hv = hp[(size_t)cl * HW];
    const float* wr = &wlds[cb + cl][0];  // wave-uniform address -> broadcast
    float4 wa = *(const float4*)(wr + 0);
    float4 wb = *(const float4*)(wr + 4);
    float4 wc = *(const float4*)(wr + 8);
    float4 wd = *(const float4*)(wr + 12);
    float2 we = *(const float2*)(wr + 16);
    acc[0]  = fmaf(hv, wa.x, acc[0]);  acc[1]  = fmaf(hv, wa.y, acc[1]);
    acc[2]  = fmaf(hv, wa.z, acc[2]);  acc[3]  = fmaf(hv, wa.w, acc[3]);
    acc[4]  = fmaf(hv, wb.x, acc[4]);  acc[5]  = fmaf(hv, wb.y, acc[5]);
    acc[6]  = fmaf(hv, wb.z, acc[6]);  acc[7]  = fmaf(hv, wb.w, acc[7]);
    acc[8]  = fmaf(hv, wc.x, acc[8]);  acc[9]  = fmaf(hv, wc.y, acc[9]);
    acc[10] = fmaf(hv, wc.z, acc[10]); acc[11] = fmaf(hv, wc.w, acc[11]);
    acc[12] = fmaf(hv, wd.x, acc[12]); acc[13] = fmaf(hv, wd.y, acc[13]);
    acc[14] = fmaf(hv, wd.z, acc[14]); acc[15] = fmaf(hv, wd.w, acc[15]);
    acc[16] = fmaf(hv, we.x, acc[16]); acc[17] = fmaf(hv, we.y, acc[17]);
  }
  if (sl == 1) {
#pragma unroll
    for (int j = 0; j < 18; ++j) part[pl][j] = acc[j];
  }
  __syncthreads();
  if (sl == 0) {
    int s = s0 + pl;
#pragma unroll
    for (int j = 0; j < 18; ++j) {
      float v = acc[j] + part[pl][j];  // sl0-chain + sl1-chain (order as before)
      hacc[(size_t)(kg * 18 + j) * (NB * HW) + (size_t)n * HW + s] = v;
    }
  }
}

// ---------------- K2b: heads epilogue (verbatim arithmetic) ----------------
__global__ __launch_bounds__(256) void heads_epi(
    const float* __restrict__ hacc, const float* __restrict__ sb,
    const float* __restrict__ lb, float* __restrict__ out,
    float* __restrict__ fgm, float* __restrict__ boxes) {
  int g = blockIdx.x * 256 + threadIdx.x;  // 0..32767
  int n = g >> 12;
  int s = g & 4095;
  float acc[54];
#pragma unroll
  for (int k = 0; k < 54; ++k)
    acc[k] = hacc[(size_t)k * (NB * HW) + (size_t)n * HW + s];
  int y = s >> 6, xx = s & 63;
  float sc[18], lo[36];
#pragma unroll
  for (int k = 0; k < 18; k++) sc[k] = acc[k] + sb[k];
#pragma unroll
  for (int k = 0; k < 36; k++) lo[k] = acc[18 + k] + lb[k];
  size_t base = (size_t)n * NANC + (size_t)s * 9;
#pragma unroll
  for (int i = 0; i < 36; i++) out[OUT_LOCS + base * 4 + i] = lo[i];
#pragma unroll
  for (int i = 0; i < 18; i++) out[OUT_SCORES + base * 2 + i] = sc[i];
  float syf = (float)(y * 16), sxf = (float)(xx * 16);
#pragma unroll
  for (int a = 0; a < 9; a++) {
    float s0v = sc[a * 2], s1v = sc[a * 2 + 1];
    float m = fmaxf(s0v, s1v);
    float e0 = expf(s0v - m), e1 = expf(s1v - m);
    float fg = e1 / (e0 + e1);
    int ri = a / 3, si = a - ri * 3;
    double r = (ri == 0) ? 0.5 : (ri == 1 ? 1.0 : 2.0);
    double scd = (si == 0) ? 8.0 : (si == 1 ? 16.0 : 32.0);
    double hhd = 16.0 * scd * sqrt(r);
    double wwd = 16.0 * scd * sqrt(1.0 / r);
    float a0 = (float)(8.0 - hhd * 0.5) + syf;
    float a1 = (float)(8.0 - wwd * 0.5) + sxf;
    float a2 = (float)(8.0 + hhd * 0.5) + syf;
    float a3 = (float)(8.0 + wwd * 0.5) + sxf;
    float hA = a2 - a0, wA = a3 - a1;
    float cy = a0 + 0.5f * hA, cx = a1 + 0.5f * wA;
    float dy = lo[a * 4 + 0], dx = lo[a * 4 + 1];
    float dh = lo[a * 4 + 2], dw = lo[a * 4 + 3];
    float cy2 = dy * hA + cy, cx2 = dx * wA + cx;
    float h2 = expf(dh) * hA, w2 = expf(dw) * wA;
    float b0 = cy2 - 0.5f * h2, b1 = cx2 - 0.5f * w2;
    float b2 = cy2 + 0.5f * h2, b3 = cx2 + 0.5f * w2;
    b0 = fminf(fmaxf(b0, 0.f), 1024.f);
    b1 = fminf(fmaxf(b1, 0.f), 1024.f);
    b2 = fminf(fmaxf(b2, 0.f), 1024.f);
    b3 = fminf(fmaxf(b3, 0.f), 1024.f);
    float hs = b2 - b0, wss = b3 - b1;
    bool valid = (hs >= 16.f) && (wss >= 16.f);
    size_t bi = base + a;
    boxes[bi * 4 + 0] = b0; boxes[bi * 4 + 1] = b1;
    boxes[bi * 4 + 2] = b2; boxes[bi * 4 + 3] = b3;
    fgm[bi] = valid ? fg : -__builtin_inff();
  }
}

// ---------------- K3: top-2000 (4-pass radix on 32-bit orderable score) ----------------
__device__ __forceinline__ uint32_t ord32(float v) {
  uint32_t s = __float_as_uint(v);
  return (s & 0x80000000u) ? ~s : (s | 0x80000000u);
}

__global__ __launch_bounds__(1024) void select2_kernel(
    const float* __restrict__ fgm, const float* __restrict__ boxes,
    float4* __restrict__ selb, uint8_t* __restrict__ selv) {
  int n = blockIdx.x;
  const float* f = fgm + (size_t)n * NANC;
  __shared__ uint32_t hist[256];
  __shared__ uint32_t segsum[16], segsufE[16];
  __shared__ uint64_t keys[2048];
  __shared__ uint32_t sh_digit, sh_T, scnt;
  int tid = threadIdx.x;
  uint32_t pref = 0;
  uint32_t T = PRE;
  for (int p = 0; p < 4; ++p) {
    int shift = 24 - 8 * p;
    if (tid < 256) hist[tid] = 0;
    __syncthreads();
    for (int i = tid; i < NANC; i += 1024) {
      uint32_t u = ord32(f[i]);
      bool match = (p == 0) || ((u >> (shift + 8)) == (pref >> (shift + 8)));
      if (match) atomicAdd(&hist[(u >> shift) & 255u], 1u);
    }
    __syncthreads();
    if (tid < 16) {
      uint32_t s = 0;
      for (int j = 0; j < 16; ++j) s += hist[tid * 16 + j];
      segsum[tid] = s;
    }
    __syncthreads();
    if (tid == 0) {
      uint32_t run = 0;
      for (int s = 15; s >= 0; --s) { segsufE[s] = run; run += segsum[s]; }
    }
    __syncthreads();
    if (tid < 256) {
      int d = tid, s = d >> 4;
      uint32_t loc = 0;
      for (int j = d; j < (s + 1) * 16; ++j) loc += hist[j];
      uint32_t suf = segsufE[s] + loc;
      uint32_t sufn = suf - hist[d];
      if (suf >= T && sufn < T) { sh_digit = (uint32_t)d; sh_T = T - sufn; }
    }
    __syncthreads();
    pref |= sh_digit << shift;
    T = sh_T;
    __syncthreads();
  }
  if (tid == 0) scnt = 0;
  __syncthreads();
  for (int i = tid; i < NANC; i += 1024) {
    uint32_t u = ord32(f[i]);
    if (u >= pref) {
      uint32_t pos = atomicAdd(&scnt, 1u);
      if (pos < 2048) keys[pos] = ((uint64_t)u << 32) | (uint32_t)(~(uint32_t)i);
    }
  }
  __syncthreads();
  uint32_t sc = scnt > 2048 ? 2048 : scnt;
  for (int i = sc + tid; i < 2048; i += 1024) keys[i] = 0;
  __syncthreads();
  for (int k = 2; k <= 2048; k <<= 1) {
    for (int j = k >> 1; j > 0; j >>= 1) {
      for (int e = tid; e < 2048; e += 1024) {
        int partner = e ^ j;
        if (partner > e) {
          bool up = ((e & k) == 0);
          uint64_t a = keys[e], b = keys[partner];
          if (up ? (a < b) : (a > b)) { keys[e] = b; keys[partner] = a; }
        }
      }
      __syncthreads();
    }
  }
  for (int t2 = tid; t2 < PRE; t2 += 1024) {
    uint64_t key = keys[t2];
    uint32_t idx = ~((uint32_t)(key & 0xFFFFFFFFu));
    const float4* bp = (const float4*)(boxes + ((size_t)n * NANC + idx) * 4);
    selb[(size_t)n * 2048 + t2] = *bp;
    selv[(size_t)n * 2048 + t2] = ((uint32_t)(key >> 32)) > 0x007FFFFFu ? 1 : 0;
  }
}

// ---------------- K4a: NMS suppression mask (grid-parallel) ----------------
__global__ __launch_bounds__(256) void nms_mask_kernel(
    const float4* __restrict__ selb, uint64_t* __restrict__ mask) {
  __shared__ float by0[PRE], bx0_[PRE], by1[PRE], bx1_[PRE], bar[PRE];
  int b = blockIdx.x;
  int n = b / 250;
  int i0 = (b % 250) * 8;
  int tid = threadIdx.x;
  for (int j = tid; j < PRE; j += 256) {
    float4 bb = selb[(size_t)n * 2048 + j];
    by0[j] = bb.x; bx0_[j] = bb.y; by1[j] = bb.z; bx1_[j] = bb.w;
    bar[j] = (bb.z - bb.x) * (bb.w - bb.y);
  }
  __syncthreads();
  int i = i0 + (tid >> 5);
  int jw = tid & 31;
  float iy0 = by0[i], ix0 = bx0_[i], iy1 = by1[i], ix1 = bx1_[i], ia = bar[i];
  uint64_t bits = 0;
  int jb = jw * 64;
  for (int tb = 0; tb < 64; ++tb) {
    int tbp = (tb + jw) & 63;
    int j = jb + tbp;
    if (j < PRE && j > i) {
      float ty = fmaxf(iy0, by0[j]);
      float txx = fmaxf(ix0, bx0_[j]);
      float byv = fminf(iy1, by1[j]);
      float bxv = fminf(ix1, bx1_[j]);
      float ih = byv - ty; if (ih < 0.f) ih = 0.f;
      float iw = bxv - txx; if (iw < 0.f) iw = 0.f;
      float inter = ih * iw;
      float iou = inter / (ia + bar[j] - inter + 1e-9f);
      if (iou > 0.7f) bits |= (1ull << tbp);
    }
  }
  mask[((size_t)n * PRE + i) * 32 + jw] = bits;
}

// ---------------- K4b: NMS bit-scan, PREFETCHED all-rows (R19) ----------------
// R19: R18's speculation failed (163us): the next-in-score candidate is
// exactly the near-duplicate most likely suppressed by the previous kept box
// (survival ~1-2/8), so it degenerated to the serial chain + extraction
// overhead. Static addresses beat prediction: process ALL 2000 rows in order
// (R16 semantics) but with (a) double-buffered 20-row half-batches so the
// next batch's loads overlap this batch's processing (R16 stalled ~900cyc
// per batch), and (b) BRANCHLESS per-row processing (shfl + bit-test +
// cndmask + add) with a batch-level POST check: snapshot (kw,csf) before
// each half-batch; if csf>=POST at batch end, restore and REPLAY that batch
// with exact per-row semantics. Divergence from true processing can only
// start at the row where csf hits POST (csf monotone, identical before it)
// -> detection guaranteed, replay exact -> bit-identical istar/kw/outputs.
#define NSB 20  // rows per half-batch; 2000 = 50 x 2 x NSB exactly
__global__ __launch_bounds__(64) void nms_scan_kernel(
    const uint8_t* __restrict__ selv, const uint64_t* __restrict__ mask,
    const float4* __restrict__ selb, float* __restrict__ out) {
  int n = blockIdx.x;
  int lane = threadIdx.x;
  const uint8_t* sv = selv + (size_t)n * 2048;
  uint64_t kw = 0;
  for (int wblk = 0; wblk < 32; ++wblk) {
    int j = wblk * 64 + lane;
    bool pred = (j < PRE) && (sv[j] != 0);
    uint64_t m = __ballot(pred);
    if (lane == wblk) kw = m;
  }
  const uint64_t* mrow = mask + (size_t)n * PRE * 32;
  int istar = PRE - 1;
  int csf = 0;
  bool done = false;

  uint64_t rA[NSB], rB[NSB];

#define LOADB(rr, i0)                                                      \
  do {                                                                     \
    int _i0 = (i0);                                                        \
    _Pragma("unroll")                                                      \
    for (int _t = 0; _t < NSB; ++_t) {                                     \
      int _ri = _i0 + _t;                                                  \
      if (_ri >= PRE) _ri = 0; /* clamp: value unused (done by then) */    \
      rr[_t] = (lane < 32) ? mrow[(size_t)_ri * 32 + lane] : 0ull;         \
    }                                                                      \
  } while (0)

#define PROCB(rr, i0)                                                      \
  do {                                                                     \
    if (!done) {                                                           \
      int _i0 = (i0);                                                      \
      uint64_t _kw0 = kw;                                                  \
      int _csf0 = csf;                                                     \
      _Pragma("unroll")                                                    \
      for (int _t = 0; _t < NSB; ++_t) {                                   \
        int _i = _i0 + _t;                                                 \
        uint64_t _w = __shfl(kw, _i >> 6);                                 \
        uint64_t _keep = (_w >> (_i & 63)) & 1ull;                         \
        kw &= _keep ? ~rr[_t] : ~0ull;                                     \
        csf += (int)_keep;                                                 \
      }                                                                    \
      if (csf >= POST) { /* rare: restore + exact replay */                \
        kw = _kw0; csf = _csf0;                                            \
        _Pragma("unroll")                                                  \
        for (int _t = 0; _t < NSB; ++_t) {                                 \
          int _i = _i0 + _t;                                               \
          if (!done) {                                                     \
            uint64_t _w = __shfl(kw, _i >> 6);                             \
            if ((_w >> (_i & 63)) & 1ull) {                                \
              csf++;                                                       \
              if (csf >= POST) { istar = _i; done = true; }                \
              else kw &= ~rr[_t];                                          \
            }                                                              \
          }                                                                \
        }                                                                  \
      }                                                                    \
    }                                                                      \
  } while (0)

  LOADB(rA, 0);
#pragma unroll 1
  for (int i0 = 0; i0 < PRE; i0 += 2 * NSB) {
    LOADB(rB, i0 + NSB);       // prefetch next half-batch (overlaps PROCB(rA))
    PROCB(rA, i0);
    LOADB(rA, i0 + 2 * NSB);   // prefetch next-next (clamped at end; unused if done)
    PROCB(rB, i0 + NSB);
    if (done) break;
  }
#undef LOADB
#undef PROCB

  // mask off indices beyond istar
  int wordi = istar >> 6, biti = istar & 63;
  uint64_t km = (lane < wordi) ? ~0ull
              : (lane == wordi ? ((biti == 63) ? ~0ull : ((1ull << (biti + 1)) - 1ull)) : 0ull);
  uint64_t kwv = (lane < 32) ? (kw & km) : 0ull;
  int pc = __popcll(kwv);
  int pre = pc;
  for (int d = 1; d < 64; d <<= 1) {
    int v = __shfl_up(pre, d);
    if (lane >= d) pre += v;
  }
  int total = __shfl(pre, 63);
  int rank = pre - pc;
  uint64_t bits = kwv;
  while (bits) {
    int bpos = __ffsll((unsigned long long)bits) - 1;
    bits &= bits - 1;
    if (rank < POST) {
      int j = lane * 64 + bpos;
      float4 bx = selb[(size_t)n * 2048 + j];
      size_t o = (size_t)OUT_ROIS + ((size_t)n * POST + rank) * 4;
      out[o + 0] = bx.x; out[o + 1] = bx.y; out[o + 2] = bx.z; out[o + 3] = bx.w;
    }
    rank++;
  }
  int cnt = total > POST ? POST : total;
  for (int r2 = cnt + lane; r2 < POST; r2 += 64) {
    size_t o = (size_t)OUT_ROIS + ((size_t)n * POST + r2) * 4;
    out[o + 0] = 0.f; out[o + 1] = 0.f; out[o + 2] = 0.f; out[o + 3] = 0.f;
  }
  for (int r2 = lane; r2 < POST; r2 += 64)
    out[OUT_RIDX + n * POST + r2] = (float)n;
}

extern "C" void kernel_launch(void* const* d_in, const int* in_sizes, int n_in,
                              void* d_out, int out_size, void* d_ws, size_t ws_size,
                              hipStream_t stream) {
  const float* x   = (const float*)d_in[0];
  const float* c1w = (const float*)d_in[1];
  const float* c1b = (const float*)d_in[2];
  const float* sw  = (const float*)d_in[3];
  const float* sb  = (const float*)d_in[4];
  const float* lw  = (const float*)d_in[5];
  const float* lb  = (const float*)d_in[6];
  float* out = (float*)d_out;
  char* ws = (char*)d_ws;
  float*     hbuf = (float*)(ws);                        // 67,108,864 B
  float*     fgm  = (float*)(ws + 67108864);             // 1,179,648 B
  float*     boxes= (float*)(ws + 68288512);             // 4,718,592 B
  _Float16*  Bf   = (_Float16*)(ws + 73007104);          // 9,437,184 B
  float*     hacc = (float*)(ws + 73007104);             // aliases Bf: conv done before heads_mm (stream-ordered); 7,077,888 B <= 9,437,184 B
  float4*    selb = (float4*)(ws + 82444288);            // 262,144 B
  uint8_t*   selv = (uint8_t*)(ws + 82706432);           // 16,384 B
  uint64_t*  mask = (uint64_t*)(ws + 82722816);          // 4,096,000 B

  anchor_kernel<<<144, 256, 0, stream>>>(out);
  wprep_kernel<<<18432, 256, 0, stream>>>(c1w, Bf);
  // diagnostic 4-way split: bit-identical to one 2048-block dispatch
  conv3_mfma<<<512, 256, 0, stream>>>(x, Bf, c1b, hbuf, 0);
  conv3_mfma<<<512, 256, 0, stream>>>(x, Bf, c1b, hbuf, 512);
  conv3_mfma<<<512, 256, 0, stream>>>(x, Bf, c1b, hbuf, 1024);
  conv3_mfma<<<512, 256, 0, stream>>>(x, Bf, c1b, hbuf, 1536);
  heads_mm<<<768, 256, 0, stream>>>(hbuf, sw, lw, hacc);
  heads_epi<<<128, 256, 0, stream>>>(hacc, sb, lb, out, fgm, boxes);
  select2_kernel<<<8, 1024, 0, stream>>>(fgm, boxes, selb, selv);
  nms_mask_kernel<<<2000, 256, 0, stream>>>(selb, mask);
  nms_scan_kernel<<<8, 64, 0, stream>>>(selv, mask, selb, out);
}